// Round 10
// baseline (995.357 us; speedup 1.0000x reference)
//
#include <hip/hip_runtime.h>

#define NN 100000
#define NE 1600000
#define ND 64
#define HD 128
#define NPB 8              // nodes per fine bucket (one wave owns one bucket)
#define NBK (NN / NPB)     // 12500 fine buckets
#define NPCB 400           // nodes per coarse bucket (multiple of NPB)
#define NCB 250            // coarse buckets = NN/NPCB exactly
#define NFPC (NPCB / NPB)  // 50 fine buckets per coarse
#define NBA 64             // pass-A scatter blocks
#define CHA (NE / NBA)     // 25000 edges per pass-A block
#define MSC (NCB * NBA)    // scan length = 16000
#define CSC 16             // scan elems per thread (1024*16 >= MSC)

typedef float f32x4 __attribute__((ext_vector_type(4)));
typedef short s16x8 __attribute__((ext_vector_type(8)));

// packed edge record: x = src | (dloc << 17)  (src < 2^17, dloc < 400 < 2^9)
//                     y = edge_attr f32 bits

// round-to-nearest-even fp32 -> bf16 (raw short)
static __device__ __forceinline__ short f2bf(float f) {
    union { float f; unsigned u; } v; v.f = f;
    unsigned r = (v.u + 0x7fffu + ((v.u >> 16) & 1u)) >> 16;
    return (short)r;
}

// swizzled LDS index, 128-col tiles (16B chunk ^ row) -> conflict-free b128
#define LSW(n, k)  (((n) << 7) + ((((k) >> 3) ^ ((n) & 15)) << 3) + ((k) & 7))
// swizzled LDS index, 64-col tiles
#define LSW64(n, k) (((n) << 6) + ((((k) >> 3) ^ ((n) & 7)) << 3) + ((k) & 7))

// ---------------------------------------------------------------------------
// histA: per-block coarse-bucket counts (LDS atomics only) + folded-in
// conv_bf16 (independent work; hides under histogram latency)
// ---------------------------------------------------------------------------
__global__ __launch_bounds__(1024) void histA(const int* __restrict__ ei,
                                              int* __restrict__ gHistA,
                                              const float* __restrict__ x,
                                              short* __restrict__ xb) {
    __shared__ int h[NCB];
    const int tid = threadIdx.x;
    if (tid < NCB) h[tid] = 0;
    __syncthreads();
    const int base = blockIdx.x * CHA;
    for (int i = tid; i < CHA; i += 1024)
        atomicAdd(&h[ei[NE + base + i] / NPCB], 1);
    __syncthreads();
    if (tid < NCB) gHistA[tid * NBA + blockIdx.x] = h[tid];

    // ---- conv: x fp32 -> xb bf16 (grid-stride over all groups) ----
    const int NG = NN * ND / 8;   // 800000 groups of 8
    for (int g = blockIdx.x * 1024 + tid; g < NG; g += NBA * 1024) {
        const float4 a = ((const float4*)x)[g * 2];
        const float4 b = ((const float4*)x)[g * 2 + 1];
        s16x8 o;
        o[0] = f2bf(a.x); o[1] = f2bf(a.y); o[2] = f2bf(a.z); o[3] = f2bf(a.w);
        o[4] = f2bf(b.x); o[5] = f2bf(b.y); o[6] = f2bf(b.z); o[7] = f2bf(b.w);
        ((s16x8*)xb)[g] = o;
    }
}

// ---------------------------------------------------------------------------
// scanA: in-place exclusive scan of gHistA (16000 ints), one block
// ---------------------------------------------------------------------------
__global__ __launch_bounds__(1024) void scanA(int* __restrict__ g,
                                              int* __restrict__ ticket) {
    __shared__ int A[1024], B[1024];
    const int t  = threadIdx.x;
    const int i0 = t * CSC;
    const int i1 = min(i0 + CSC, MSC);
    int s = 0;
    for (int i = i0; i < i1; ++i) s += g[i];
    A[t] = s;
    __syncthreads();
    int* src = A; int* dst = B;
    for (int off = 1; off < 1024; off <<= 1) {
        int val = src[t];
        if (t >= off) val += src[t - off];
        dst[t] = val;
        __syncthreads();
        int* tmp = src; src = dst; dst = tmp;
    }
    int run = t ? src[t - 1] : 0;
    for (int i = i0; i < i1; ++i) {
        const int v = g[i];
        g[i] = run; run += v;
    }
    if (t == 0) *ticket = 0;
}

// ---------------------------------------------------------------------------
// scatterA: bin edges into 250 coarse buckets as packed 8B records;
// per-(bucket,block) runs are ~100 edges contiguous -> coalesced writes.
// ---------------------------------------------------------------------------
__global__ __launch_bounds__(1024) void scatterA(
    const int* __restrict__ ei, const float* __restrict__ ea,
    const int* __restrict__ gBaseA, int2* __restrict__ tsd) {
    __shared__ int cur[NCB];
    const int tid = threadIdx.x;
    if (tid < NCB) cur[tid] = gBaseA[tid * NBA + blockIdx.x];
    __syncthreads();
    const int base = blockIdx.x * CHA;
    for (int i = tid; i < CHA; i += 1024) {
        const int e = base + i;
        const int sv = ei[e], d = ei[NE + e];
        const float av = ea[e];
        const int c = d / NPCB;
        const int dloc = d - c * NPCB;
        const int pos = atomicAdd(&cur[c], 1);
        tsd[pos] = make_int2(sv | (dloc << 17), __float_as_int(av));
    }
}

// ---------------------------------------------------------------------------
// scatterB: one block per coarse bucket (250 blocks = 97.7% of CUs).
// Self-counts the 400-node histogram from tsd (LDS atomics), LDS-scans it,
// writes rowptrB at 8-node boundaries, then permutes the bucket's PACKED
// records into dst-sorted order: one 8B write per edge, L2-resident.
// ---------------------------------------------------------------------------
__global__ __launch_bounds__(1024) void scatterB(
    const int2* __restrict__ tsd, const int* __restrict__ gBaseA,
    int2* __restrict__ rsd, int* __restrict__ rowptrB) {
    __shared__ int h[NPCB];
    __shared__ int cur[NPCB];
    __shared__ int A[512], B[512];
    const int c = blockIdx.x;
    const int t = threadIdx.x;
    const int nb0  = c * NPCB;
    const int base = gBaseA[c * NBA];
    const int endc = (c + 1 < NCB) ? gBaseA[(c + 1) * NBA] : NE;

    if (t < NPCB) h[t] = 0;
    __syncthreads();
    for (int i = base + t; i < endc; i += 1024)
        atomicAdd(&h[(tsd[i].x >> 17) & 0x1FF], 1);
    __syncthreads();

    // exclusive scan of 400 counts over 512 lanes (Hillis-Steele)
    if (t < 512) A[t] = (t < NPCB) ? h[t] : 0;
    __syncthreads();
    int* src = A; int* dst = B;
    for (int off = 1; off < 512; off <<= 1) {
        if (t < 512) {
            int val = src[t];
            if (t >= off) val += src[t - off];
            dst[t] = val;
        }
        __syncthreads();
        int* tmp = src; src = dst; dst = tmp;
    }
    if (t < NPCB) {
        const int excl = t ? src[t - 1] : 0;
        cur[t] = base + excl;
        if ((t & (NPB - 1)) == 0)
            rowptrB[(nb0 + t) / NPB] = base + excl;
    }
    if (c == NCB - 1 && t == 0) rowptrB[NBK] = NE;
    __syncthreads();

    for (int i = base + t; i < endc; i += 1024) {
        const int2 r = tsd[i];
        const int pos = atomicAdd(&cur[(r.x >> 17) & 0x1FF], 1);
        rsd[pos] = r;
    }
}

// ---------------------------------------------------------------------------
// msg_mfma3: per-edge MLP on MFMA over dst-sorted packed edges.
// ROUND-10: TLP via 2 blocks/CU at 512 threads (compiler's natural 128-VGPR
// budget — r9 proved 768t caps at 84 and spills). Per-block LDS cut to
// exactly 80KiB: (a) vbuf halved via two-k-half epilogue+GEMM2 split;
// (b) vf/vals/readlane reduce replaced by 16 masked LDS atomicAdds into al
// (bank-staggered by row&3) — also removes the r8 serial chain tail.
// LDS: 32K(w1)+16K(w2)+8x2K(vbuf)+8x2K(al) = 81,920B = 160KiB/2 exactly.
// ---------------------------------------------------------------------------
__global__ __launch_bounds__(512) void msg_mfma3(
    const short* __restrict__ xb, const int2* __restrict__ rsd,
    const int* __restrict__ rowptrB, int* __restrict__ ticket,
    const float* __restrict__ W1, const float* __restrict__ b1,
    const float* __restrict__ W2, const float* __restrict__ b2,
    float* __restrict__ aggr)
{
    __shared__ short w1lds[128 * 128];        // 32 KB
    __shared__ short w2lds[64 * 128];         // 16 KB
    __shared__ short vbuf[8 * 16 * 64];       // 16 KB (16x64 per wave)
    __shared__ float albuf[8 * NPB * 64];     // 16 KB bucket-local aggr

    const int tid = threadIdx.x;
    for (int i = tid; i < 128 * 128; i += 512) {
        int n = i >> 7, k = i & 127;
        w1lds[LSW(n, k)] = f2bf(W1[n * 129 + k]);
    }
    for (int i = tid; i < 64 * 128; i += 512) {
        int n = i >> 7, k = i & 127;
        w2lds[LSW(n, k)] = f2bf(W2[n * 128 + k]);
    }
    __syncthreads();

    const int lane = tid & 63;
    const int w    = tid >> 6;
    const int nlo  = lane & 15;
    const int q    = lane >> 4;

    float w1l[8], b1v[8], b2v[4];
    #pragma unroll
    for (int t = 0; t < 8; ++t) {
        w1l[t] = W1[(nlo + 16 * t) * 129 + 128];
        b1v[t] = b1[nlo + 16 * t];
    }
    #pragma unroll
    for (int t = 0; t < 4; ++t) b2v[t] = b2[nlo + 16 * t];

    short* myv = vbuf + w * (16 * 64);
    float* al  = albuf + w * (NPB * 64);

    for (;;) {
        int bk = 0;
        if (lane == 0) bk = atomicAdd(ticket, 1);
        bk = __shfl(bk, 0, 64);
        if (bk >= NBK) break;

        const int n0    = bk * NPB;           // global first node of bucket
        const int cbase = (bk / NFPC) * NPCB; // coarse-bucket node base
        const int bdl   = (bk % NFPC) * NPB;  // dloc base of this fine bucket
        const int start = rowptrB[bk];
        const int end   = rowptrB[bk + 1];

        // zero bucket accumulator (8x64 f32)
        const f32x4 z = {0.f, 0.f, 0.f, 0.f};
        #pragma unroll
        for (int j = 0; j < 2; ++j) ((f32x4*)al)[lane + 64 * j] = z;

        if (start < end) {
            // ---- pipeline prologue: records for tiles 0,1 + tile-0 gathers ----
            int2 e0 = rsd[min(start + nlo, end - 1)];
            int2 e1 = rsd[min(start + 16 + nlo, end - 1)];
            const int sr0 = (e0.x & 0x1FFFF) * ND + (q << 3);
            const int dr0 = (cbase + ((e0.x >> 17) & 0x1FF)) * ND + (q << 3);
            s16x8 a0 = *(const s16x8*)(xb + sr0);
            s16x8 a1 = *(const s16x8*)(xb + sr0 + 32);
            s16x8 a2 = *(const s16x8*)(xb + dr0);
            s16x8 a3 = *(const s16x8*)(xb + dr0 + 32);

            for (int p = start; p < end; p += 16) {
                // ---- issue tile p+32 record + tile p+16 gathers ----
                const int2 e2 = rsd[min(p + 32 + nlo, end - 1)];
                const int sr1 = (e1.x & 0x1FFFF) * ND + (q << 3);
                const int dr1 = (cbase + ((e1.x >> 17) & 0x1FF)) * ND + (q << 3);
                const s16x8 n0_ = *(const s16x8*)(xb + sr1);
                const s16x8 n1_ = *(const s16x8*)(xb + sr1 + 32);
                const s16x8 n2_ = *(const s16x8*)(xb + dr1);
                const s16x8 n3_ = *(const s16x8*)(xb + dr1 + 32);

                const int   dlv = (e0.x >> 17) & 0x1FF;
                const float eav = __int_as_float(e0.y);

                // ---- GEMM1: h = [x_src;x_dst] @ W1^T + b1 ----
                f32x4 acc[8];
                #pragma unroll
                for (int t = 0; t < 8; ++t) { acc[t][0] = b1v[t]; acc[t][1] = b1v[t]; acc[t][2] = b1v[t]; acc[t][3] = b1v[t]; }

                __builtin_amdgcn_s_setprio(1);
                #pragma unroll
                for (int kk = 0; kk < 4; ++kk) {
                    const s16x8 af = (kk == 0) ? a0 : (kk == 1) ? a1 : (kk == 2) ? a2 : a3;
                    const int chunk = ((kk * 4 + q) ^ nlo) << 3;
                    #pragma unroll
                    for (int t = 0; t < 8; ++t) {
                        const s16x8 bf = *(const s16x8*)(w1lds + ((nlo + 16 * t) << 7) + chunk);
                        acc[t] = __builtin_amdgcn_mfma_f32_16x16x32_bf16(af, bf, acc[t], 0, 0, 0);
                    }
                }
                __builtin_amdgcn_s_setprio(0);

                float ear[4];
                #pragma unroll
                for (int r = 0; r < 4; ++r) ear[r] = __shfl(eav, q * 4 + r, 64);

                // ---- epilogue + GEMM2 in two k-halves (vbuf = 16x64) ----
                f32x4 acc2[4];
                #pragma unroll
                for (int t = 0; t < 4; ++t) { acc2[t][0] = b2v[t]; acc2[t][1] = b2v[t]; acc2[t][2] = b2v[t]; acc2[t][3] = b2v[t]; }

                #pragma unroll
                for (int half = 0; half < 2; ++half) {
                    // epilogue half: t = half*4 .. half*4+3 -> k64 = nlo+16*tt
                    #pragma unroll
                    for (int tt = 0; tt < 4; ++tt) {
                        const int t = half * 4 + tt;
                        #pragma unroll
                        for (int r = 0; r < 4; ++r) {
                            const float hv = fmaxf(acc[t][r] + ear[r] * w1l[t], 0.f);
                            const int m = q * 4 + r;
                            myv[LSW64(m, nlo + 16 * tt)] = f2bf(hv);
                        }
                    }
                    // GEMM2 half: kk_loc 0..1 (A from 64-col vbuf), kkg = half*2+kk_loc (B)
                    __builtin_amdgcn_s_setprio(1);
                    #pragma unroll
                    for (int kkl = 0; kkl < 2; ++kkl) {
                        const int achunk = ((kkl * 4 + q) ^ (nlo & 7)) << 3;
                        const s16x8 af = *(const s16x8*)(myv + (nlo << 6) + achunk);
                        const int kkg = half * 2 + kkl;
                        const int bchunk = ((kkg * 4 + q) ^ nlo) << 3;
                        #pragma unroll
                        for (int t = 0; t < 4; ++t) {
                            const s16x8 bf = *(const s16x8*)(w2lds + ((nlo + 16 * t) << 7) + bchunk);
                            acc2[t] = __builtin_amdgcn_mfma_f32_16x16x32_bf16(af, bf, acc2[t], 0, 0, 0);
                        }
                    }
                    __builtin_amdgcn_s_setprio(0);
                }

                // ---- accumulate acc2 directly into al (LDS atomics; masked) ----
                int dl_[4];
                #pragma unroll
                for (int r = 0; r < 4; ++r) dl_[r] = __shfl(dlv, q * 4 + r, 64);
                #pragma unroll
                for (int t = 0; t < 4; ++t) {
                    #pragma unroll
                    for (int r = 0; r < 4; ++r) {
                        const float v = (p + q * 4 + r < end) ? acc2[t][r] : 0.f;
                        const int row = dl_[r] - bdl;   // 0..7
                        // bank stagger: 16-col granule XORed with row&3
                        atomicAdd(&al[row * 64 + (((t ^ (row & 3)) << 4) | nlo)], v);
                    }
                }

                // ---- rotate pipeline regs ----
                e0 = e1; e1 = e2;
                a0 = n0_; a1 = n1_; a2 = n2_; a3 = n3_;
            }
        }

        // ---- flush: exclusive bucket ownership -> coalesced stores (unswizzle) ----
        #pragma unroll
        for (int j = 0; j < 2; ++j) {
            const int i   = lane + 64 * j;      // f32x4 index within 8x64
            const int row = i >> 4;             // local node 0..7
            const int c4  = (i & 15) * 4;       // col (multiple of 4)
            const f32x4 val = *(const f32x4*)(al + row * 64 + (c4 ^ ((row & 3) << 4)));
            *(f32x4*)(aggr + (n0 + row) * 64 + c4) = val;
        }
    }
}

// ---------------------------------------------------------------------------
// gru_mfma: GRUCell on MFMA. wave = 16 nodes; 2 GEMMs [16x64]@[64x192] bf16.
// ---------------------------------------------------------------------------
__global__ __launch_bounds__(512) void gru_mfma(
    const float* __restrict__ x, const float* __restrict__ aggr,
    const float* __restrict__ Wih, const float* __restrict__ bih,
    const float* __restrict__ Whh, const float* __restrict__ bhh,
    float* __restrict__ out)
{
    __shared__ short wi[192 * 64];
    __shared__ short wh[192 * 64];

    const int tid = threadIdx.x;
    for (int i = tid; i < 192 * 64; i += 512) {
        int n = i >> 6, k = i & 63;
        wi[LSW64(n, k)] = f2bf(Wih[n * 64 + k]);
        wh[LSW64(n, k)] = f2bf(Whh[n * 64 + k]);
    }
    __syncthreads();

    const int lane = tid & 63;
    const int w    = tid >> 6;
    const int nlo  = lane & 15;
    const int q    = lane >> 4;

    float bi[12], bh[12];
    #pragma unroll
    for (int t = 0; t < 12; ++t) { bi[t] = bih[16 * t + nlo]; bh[t] = bhh[16 * t + nlo]; }

    const int gw = blockIdx.x * 8 + w;
    const int nw = gridDim.x * 8;

    for (int tile = gw; tile < NN / 16; tile += nw) {
        const int n0 = tile * 16;
        f32x4 ai[12], ah[12];
        #pragma unroll
        for (int t = 0; t < 12; ++t) {
            ai[t][0] = bi[t]; ai[t][1] = bi[t]; ai[t][2] = bi[t]; ai[t][3] = bi[t];
            ah[t][0] = bh[t]; ah[t][1] = bh[t]; ah[t][2] = bh[t]; ah[t][3] = bh[t];
        }

        #pragma unroll
        for (int kk = 0; kk < 2; ++kk) {
            const int coff = (n0 + nlo) * ND + kk * 32 + q * 8;
            const float4 a0 = *(const float4*)(aggr + coff);
            const float4 a1 = *(const float4*)(aggr + coff + 4);
            const float4 x0 = *(const float4*)(x + coff);
            const float4 x1 = *(const float4*)(x + coff + 4);
            s16x8 fA, fX;
            fA[0] = f2bf(a0.x); fA[1] = f2bf(a0.y); fA[2] = f2bf(a0.z); fA[3] = f2bf(a0.w);
            fA[4] = f2bf(a1.x); fA[5] = f2bf(a1.y); fA[6] = f2bf(a1.z); fA[7] = f2bf(a1.w);
            fX[0] = f2bf(x0.x); fX[1] = f2bf(x0.y); fX[2] = f2bf(x0.z); fX[3] = f2bf(x0.w);
            fX[4] = f2bf(x1.x); fX[5] = f2bf(x1.y); fX[6] = f2bf(x1.z); fX[7] = f2bf(x1.w);
            const int chunk = kk * 4 + q;
            #pragma unroll
            for (int t = 0; t < 12; ++t) {
                const int rb = 16 * t + nlo;
                const int boff = (rb << 6) + (((chunk) ^ (rb & 7)) << 3);
                const s16x8 bI = *(const s16x8*)(wi + boff);
                const s16x8 bH = *(const s16x8*)(wh + boff);
                ai[t] = __builtin_amdgcn_mfma_f32_16x16x32_bf16(fA, bI, ai[t], 0, 0, 0);
                ah[t] = __builtin_amdgcn_mfma_f32_16x16x32_bf16(fX, bH, ah[t], 0, 0, 0);
            }
        }

        #pragma unroll
        for (int t = 0; t < 4; ++t) {
            #pragma unroll
            for (int r = 0; r < 4; ++r) {
                const int node = n0 + q * 4 + r;
                const int c    = nlo + 16 * t;
                const float rr = 1.f / (1.f + __expf(-(ai[t][r] + ah[t][r])));
                const float zz = 1.f / (1.f + __expf(-(ai[t + 4][r] + ah[t + 4][r])));
                const float nv = ai[t + 8][r] + rr * ah[t + 8][r];
                const float nn = 2.f / (1.f + __expf(-2.f * nv)) - 1.f;   // tanh
                const float xv = x[node * ND + c];
                out[node * ND + c] = (1.f - zz) * nn + zz * xv;
            }
        }
    }
}

extern "C" void kernel_launch(void* const* d_in, const int* in_sizes, int n_in,
                              void* d_out, int out_size, void* d_ws, size_t ws_size,
                              hipStream_t stream) {
    const float* x   = (const float*)d_in[0];
    const int*   ei  = (const int*)d_in[1];
    const float* ea  = (const float*)d_in[2];
    const float* W1  = (const float*)d_in[3];
    const float* b1  = (const float*)d_in[4];
    const float* W2  = (const float*)d_in[5];
    const float* b2  = (const float*)d_in[6];
    const float* Wih = (const float*)d_in[7];
    const float* bih = (const float*)d_in[8];
    const float* Whh = (const float*)d_in[9];
    const float* bhh = (const float*)d_in[10];
    float* out = (float*)d_out;

    // workspace layout (~51.4 MB)
    char* ws = (char*)d_ws;
    float* aggr    = (float*)(ws);                 // 25,600,000 B (msg output)
    // tmp packed-edge buffer aliases onto aggr (dead before msg writes it):
    int2*  tsd     = (int2*) (ws);                 // 12,800,000 B
    short* xb      = (short*)(ws + 25600000);      // 12,800,000 B
    int2*  rsd     = (int2*) (ws + 38400000);      // 12,800,000 B packed sorted
    int*   gHistA  = (int*)  (ws + 51200000);      //     64,000 B (250*64 ints)
    int*   rowptrB = (int*)  (ws + 51264000);      //     50,004 B (12501 ints)
    int*   ticket  = (int*)  (ws + 51314004);      //          4 B

    hipLaunchKernelGGL(histA, dim3(NBA), dim3(1024), 0, stream, ei, gHistA, x, xb);
    hipLaunchKernelGGL(scanA, dim3(1), dim3(1024), 0, stream, gHistA, ticket);
    hipLaunchKernelGGL(scatterA, dim3(NBA), dim3(1024), 0, stream,
                       ei, ea, gHistA, tsd);
    hipLaunchKernelGGL(scatterB, dim3(NCB), dim3(1024), 0, stream,
                       tsd, gHistA, rsd, rowptrB);
    hipLaunchKernelGGL(msg_mfma3, dim3(512), dim3(512), 0, stream,
                       xb, rsd, rowptrB, ticket, W1, b1, W2, b2, aggr);
    hipLaunchKernelGGL(gru_mfma, dim3(512), dim3(512), 0, stream,
                       x, aggr, Wih, bih, Whh, bhh, out);
}

// Round 11
// 510.457 us; speedup vs baseline: 1.9499x; 1.9499x over previous
//
#include <hip/hip_runtime.h>

#define NN 100000
#define NE 1600000
#define ND 64
#define HD 128
#define NPB 16             // nodes per fine bucket (one wave owns one bucket)
#define NBK (NN / NPB)     // 6250 fine buckets
#define NPCB 400           // nodes per coarse bucket (multiple of NPB!)
#define NCB 250            // coarse buckets = NN/NPCB exactly
#define NBA 64             // pass-A scatter blocks
#define CHA (NE / NBA)     // 25000 edges per pass-A block
#define MSC (NCB * NBA)    // scan length = 16000
#define CSC 16             // scan elems per thread (1024*16 >= MSC)

typedef float f32x4 __attribute__((ext_vector_type(4)));
typedef short s16x8 __attribute__((ext_vector_type(8)));

// round-to-nearest-even fp32 -> bf16 (raw short)
static __device__ __forceinline__ short f2bf(float f) {
    union { float f; unsigned u; } v; v.f = f;
    unsigned r = (v.u + 0x7fffu + ((v.u >> 16) & 1u)) >> 16;
    return (short)r;
}

// swizzled LDS index, 128-col tiles (16B chunk ^ row) -> conflict-free b128
#define LSW(n, k)  (((n) << 7) + ((((k) >> 3) ^ ((n) & 15)) << 3) + ((k) & 7))
// swizzled LDS index, 64-col tiles
#define LSW64(n, k) (((n) << 6) + ((((k) >> 3) ^ ((n) & 7)) << 3) + ((k) & 7))

// ---------------------------------------------------------------------------
// conv_bf16: x fp32 -> xb bf16 (once per call)
// ---------------------------------------------------------------------------
__global__ __launch_bounds__(256) void conv_bf16(const float* __restrict__ x,
                                                 short* __restrict__ xb) {
    const int NG = NN * ND / 8;   // 800000 groups of 8
    for (int g = blockIdx.x * 256 + threadIdx.x; g < NG; g += gridDim.x * 256) {
        const float4 a = ((const float4*)x)[g * 2];
        const float4 b = ((const float4*)x)[g * 2 + 1];
        s16x8 o;
        o[0] = f2bf(a.x); o[1] = f2bf(a.y); o[2] = f2bf(a.z); o[3] = f2bf(a.w);
        o[4] = f2bf(b.x); o[5] = f2bf(b.y); o[6] = f2bf(b.z); o[7] = f2bf(b.w);
        ((s16x8*)xb)[g] = o;
    }
}

// ---------------------------------------------------------------------------
// histA: per-block coarse-bucket counts (LDS atomics only; NO global per-node
// histogram — scatterB self-counts)
// ---------------------------------------------------------------------------
__global__ __launch_bounds__(1024) void histA(const int* __restrict__ ei,
                                              int* __restrict__ gHistA) {
    __shared__ int h[NCB];
    const int tid = threadIdx.x;
    if (tid < NCB) h[tid] = 0;
    __syncthreads();
    const int base = blockIdx.x * CHA;
    for (int i = tid; i < CHA; i += 1024)
        atomicAdd(&h[ei[NE + base + i] / NPCB], 1);
    __syncthreads();
    if (tid < NCB) gHistA[tid * NBA + blockIdx.x] = h[tid];
}

// ---------------------------------------------------------------------------
// scanA: in-place exclusive scan of gHistA (16000 ints), one block
// ---------------------------------------------------------------------------
__global__ __launch_bounds__(1024) void scanA(int* __restrict__ g,
                                              int* __restrict__ ticket) {
    __shared__ int A[1024], B[1024];
    const int t  = threadIdx.x;
    const int i0 = t * CSC;
    const int i1 = min(i0 + CSC, MSC);
    int s = 0;
    for (int i = i0; i < i1; ++i) s += g[i];
    A[t] = s;
    __syncthreads();
    int* src = A; int* dst = B;
    for (int off = 1; off < 1024; off <<= 1) {
        int val = src[t];
        if (t >= off) val += src[t - off];
        dst[t] = val;
        __syncthreads();
        int* tmp = src; src = dst; dst = tmp;
    }
    int run = t ? src[t - 1] : 0;
    for (int i = i0; i < i1; ++i) {
        const int v = g[i];
        g[i] = run; run += v;
    }
    if (t == 0) *ticket = 0;
}

// ---------------------------------------------------------------------------
// scatterA: bin edges into 250 coarse buckets; per-(bucket,block) runs are
// ~100 edges contiguous -> coalesced writes.
// ---------------------------------------------------------------------------
__global__ __launch_bounds__(1024) void scatterA(
    const int* __restrict__ ei, const float* __restrict__ ea,
    const int* __restrict__ gBaseA, int2* __restrict__ tsd,
    float* __restrict__ tea) {
    __shared__ int cur[NCB];
    const int tid = threadIdx.x;
    if (tid < NCB) cur[tid] = gBaseA[tid * NBA + blockIdx.x];
    __syncthreads();
    const int base = blockIdx.x * CHA;
    for (int i = tid; i < CHA; i += 1024) {
        const int e = base + i;
        const int sv = ei[e], d = ei[NE + e];
        const float av = ea[e];
        const int pos = atomicAdd(&cur[d / NPCB], 1);
        tsd[pos] = make_int2(sv, d);
        tea[pos] = av;
    }
}

// ---------------------------------------------------------------------------
// scatterB: one block per coarse bucket (250 blocks = 97.7% of CUs).
// Self-counts the 400-node histogram from tsd (LDS atomics), LDS-scans it,
// writes rowptrB at 16-node boundaries, then permutes the bucket's edges
// into dst-sorted order. Writes uncoalesced but single-XCD-L2-resident.
// ---------------------------------------------------------------------------
__global__ __launch_bounds__(1024) void scatterB(
    const int2* __restrict__ tsd, const float* __restrict__ tea,
    const int* __restrict__ gBaseA,
    int2* __restrict__ rsd, float* __restrict__ rea,
    int* __restrict__ rowptrB) {
    __shared__ int h[NPCB];
    __shared__ int cur[NPCB];
    __shared__ int A[512], B[512];
    const int c = blockIdx.x;
    const int t = threadIdx.x;
    const int nb0  = c * NPCB;
    const int base = gBaseA[c * NBA];
    const int endc = (c + 1 < NCB) ? gBaseA[(c + 1) * NBA] : NE;

    if (t < NPCB) h[t] = 0;
    __syncthreads();
    for (int i = base + t; i < endc; i += 1024)
        atomicAdd(&h[tsd[i].y - nb0], 1);
    __syncthreads();

    // exclusive scan of 400 counts over 512 lanes (Hillis-Steele)
    if (t < 512) A[t] = (t < NPCB) ? h[t] : 0;
    __syncthreads();
    int* src = A; int* dst = B;
    for (int off = 1; off < 512; off <<= 1) {
        if (t < 512) {
            int val = src[t];
            if (t >= off) val += src[t - off];
            dst[t] = val;
        }
        __syncthreads();
        int* tmp = src; src = dst; dst = tmp;
    }
    if (t < NPCB) {
        const int excl = t ? src[t - 1] : 0;
        cur[t] = base + excl;
        if ((t & (NPB - 1)) == 0)
            rowptrB[(nb0 + t) >> 4] = base + excl;
    }
    if (c == NCB - 1 && t == 0) rowptrB[NBK] = NE;
    __syncthreads();

    for (int i = base + t; i < endc; i += 1024) {
        const int2 sd = tsd[i];
        const float av = tea[i];
        const int pos = atomicAdd(&cur[sd.y - nb0], 1);
        rsd[pos] = sd;
        rea[pos] = av;
    }
}

// ---------------------------------------------------------------------------
// msg_mfma3: per-edge MLP on MFMA over dst-sorted edges; bucket-local LDS
// accumulation (zero atomics); 1-deep software pipeline on edge stream +
// xb gathers; setprio around MFMA clusters.
// [FINAL / LOCK-IN: this exact core measured 245us, 92 VGPR, FETCH 91MB,
//  WRITE 25MB, zero scratch traffic. Session-established toolchain rule:
//  the VGPR allocator budgets from block size alone (512t->128 cap) and
//  ignores LDS-forced occupancy; every restructure that raised pressure
//  past the cap (r4-6, r9 768t->84 cap, r10 longer live ranges) spilled
//  ~0.2-1.3GB/dispatch to scratch. Do not perturb this structure.]
// ---------------------------------------------------------------------------
__global__ __launch_bounds__(512) void msg_mfma3(
    const short* __restrict__ xb, const int2* __restrict__ rsd,
    const float* __restrict__ rea, const int* __restrict__ rowptrB,
    int* __restrict__ ticket,
    const float* __restrict__ W1, const float* __restrict__ b1,
    const float* __restrict__ W2, const float* __restrict__ b2,
    float* __restrict__ aggr)
{
    __shared__ short w1lds[128 * 128];        // 32 KB
    __shared__ short w2lds[64 * 128];         // 16 KB
    __shared__ short vbuf[8 * 16 * 128];      // 32 KB (f32-reused after GEMM2)
    __shared__ float albuf[8 * NPB * 64];     // 32 KB bucket-local aggr

    const int tid = threadIdx.x;
    for (int i = tid; i < 128 * 128; i += 512) {
        int n = i >> 7, k = i & 127;
        w1lds[LSW(n, k)] = f2bf(W1[n * 129 + k]);
    }
    for (int i = tid; i < 64 * 128; i += 512) {
        int n = i >> 7, k = i & 127;
        w2lds[LSW(n, k)] = f2bf(W2[n * 128 + k]);
    }
    __syncthreads();

    const int lane = tid & 63;
    const int w    = tid >> 6;
    const int nlo  = lane & 15;
    const int q    = lane >> 4;

    float w1l[8], b1v[8], b2v[4];
    #pragma unroll
    for (int t = 0; t < 8; ++t) {
        w1l[t] = W1[(nlo + 16 * t) * 129 + 128];
        b1v[t] = b1[nlo + 16 * t];
    }
    #pragma unroll
    for (int t = 0; t < 4; ++t) b2v[t] = b2[nlo + 16 * t];

    short* myv = vbuf + w * (16 * 128);
    float* vf  = (float*)myv;                 // same 4 KB, valid after GEMM2
    float* al  = albuf + w * (NPB * 64);

    for (;;) {
        int bk = 0;
        if (lane == 0) bk = atomicAdd(ticket, 1);
        bk = __shfl(bk, 0, 64);
        if (bk >= NBK) break;

        const int n0    = bk * NPB;
        const int start = rowptrB[bk];
        const int end   = rowptrB[bk + 1];

        // zero bucket accumulator (16x64 f32)
        const f32x4 z = {0.f, 0.f, 0.f, 0.f};
        #pragma unroll
        for (int j = 0; j < 4; ++j) ((f32x4*)al)[lane + 64 * j] = z;

        if (start < end) {
            // ---- pipeline prologue: tile 0 edge + gathers ----
            int  idx0 = min(start + nlo, end - 1);
            int2 sd   = rsd[idx0];
            float eav = rea[idx0];
            s16x8 a0 = *(const s16x8*)(xb + sd.x * ND + (q << 3));
            s16x8 a1 = *(const s16x8*)(xb + sd.x * ND + 32 + (q << 3));
            s16x8 a2 = *(const s16x8*)(xb + sd.y * ND + (q << 3));
            s16x8 a3 = *(const s16x8*)(xb + sd.y * ND + 32 + (q << 3));

            for (int p = start; p < end; p += 16) {
                const int dv = sd.y;

                // ---- issue next tile's edge loads (overlap with GEMM1) ----
                const int  idxn = min(p + 16 + nlo, end - 1);
                const int2 sdn  = rsd[idxn];
                const float ean = rea[idxn];

                // ---- GEMM1: h = [x_src;x_dst] @ W1^T + b1 ----
                f32x4 acc[8];
                #pragma unroll
                for (int t = 0; t < 8; ++t) { acc[t][0] = b1v[t]; acc[t][1] = b1v[t]; acc[t][2] = b1v[t]; acc[t][3] = b1v[t]; }

                __builtin_amdgcn_s_setprio(1);
                #pragma unroll
                for (int kk = 0; kk < 4; ++kk) {
                    const s16x8 af = (kk == 0) ? a0 : (kk == 1) ? a1 : (kk == 2) ? a2 : a3;
                    const int chunk = ((kk * 4 + q) ^ nlo) << 3;
                    #pragma unroll
                    for (int t = 0; t < 8; ++t) {
                        const s16x8 bf = *(const s16x8*)(w1lds + ((nlo + 16 * t) << 7) + chunk);
                        acc[t] = __builtin_amdgcn_mfma_f32_16x16x32_bf16(af, bf, acc[t], 0, 0, 0);
                    }
                }
                __builtin_amdgcn_s_setprio(0);

                // ---- issue next tile's xb gathers (hide L3 latency) ----
                const s16x8 n0_ = *(const s16x8*)(xb + sdn.x * ND + (q << 3));
                const s16x8 n1_ = *(const s16x8*)(xb + sdn.x * ND + 32 + (q << 3));
                const s16x8 n2_ = *(const s16x8*)(xb + sdn.y * ND + (q << 3));
                const s16x8 n3_ = *(const s16x8*)(xb + sdn.y * ND + 32 + (q << 3));

                // ---- epilogue1: + ea * W1[:,128], relu, bf16, transpose via LDS ----
                float ear[4];
                #pragma unroll
                for (int r = 0; r < 4; ++r) ear[r] = __shfl(eav, q * 4 + r, 64);
                #pragma unroll
                for (int t = 0; t < 8; ++t) {
                    #pragma unroll
                    for (int r = 0; r < 4; ++r) {
                        const float hv = fmaxf(acc[t][r] + ear[r] * w1l[t], 0.f);
                        const int m = q * 4 + r;
                        const int k = nlo + 16 * t;
                        myv[LSW(m, k)] = f2bf(hv);
                    }
                }

                // ---- GEMM2: m = relu(h) @ W2^T + b2 ----
                f32x4 acc2[4];
                #pragma unroll
                for (int t = 0; t < 4; ++t) { acc2[t][0] = b2v[t]; acc2[t][1] = b2v[t]; acc2[t][2] = b2v[t]; acc2[t][3] = b2v[t]; }

                __builtin_amdgcn_s_setprio(1);
                #pragma unroll
                for (int kk = 0; kk < 4; ++kk) {
                    const int chunk = ((kk * 4 + q) ^ nlo) << 3;
                    const s16x8 af = *(const s16x8*)(myv + (nlo << 7) + chunk);
                    #pragma unroll
                    for (int t = 0; t < 4; ++t) {
                        const s16x8 bf = *(const s16x8*)(w2lds + ((nlo + 16 * t) << 7) + chunk);
                        acc2[t] = __builtin_amdgcn_mfma_f32_16x16x32_bf16(af, bf, acc2[t], 0, 0, 0);
                    }
                }
                __builtin_amdgcn_s_setprio(0);

                // ---- acc2 -> vf (f32 transpose staging; q-XOR keeps banks 2-way) ----
                #pragma unroll
                for (int t = 0; t < 4; ++t) {
                    #pragma unroll
                    for (int r = 0; r < 4; ++r) {
                        const int m = q * 4 + r;
                        vf[m * 64 + ((nlo + 16 * t) ^ (q << 3))] = acc2[t][r];
                    }
                }

                // ---- per-column segmented accumulate (dst-sorted -> few RMW) ----
                const int nrows = min(16, end - p);
                float vals[16];
                #pragma unroll
                for (int r = 0; r < 16; ++r)
                    vals[r] = vf[r * 64 + (lane ^ ((r >> 2) << 3))];

                int   prev = __builtin_amdgcn_readlane(dv, 0);
                float sum  = vals[0];
                #pragma unroll
                for (int r = 1; r < 16; ++r) {
                    if (r < nrows) {
                        const int dd = __builtin_amdgcn_readlane(dv, r);
                        if (dd == prev) sum += vals[r];
                        else {
                            al[(prev - n0) * 64 + lane] += sum;
                            prev = dd; sum = vals[r];
                        }
                    }
                }
                al[(prev - n0) * 64 + lane] += sum;

                // ---- rotate pipeline regs ----
                sd = sdn; eav = ean;
                a0 = n0_; a1 = n1_; a2 = n2_; a3 = n3_;
            }
        }

        // ---- flush: exclusive bucket ownership -> plain coalesced stores ----
        f32x4* dstv = (f32x4*)(aggr + n0 * 64);
        #pragma unroll
        for (int j = 0; j < 4; ++j)
            dstv[lane + 64 * j] = ((f32x4*)al)[lane + 64 * j];
    }
}

// ---------------------------------------------------------------------------
// gru_mfma: GRUCell on MFMA. wave = 16 nodes; 2 GEMMs [16x64]@[64x192] bf16.
// ---------------------------------------------------------------------------
__global__ __launch_bounds__(512) void gru_mfma(
    const float* __restrict__ x, const float* __restrict__ aggr,
    const float* __restrict__ Wih, const float* __restrict__ bih,
    const float* __restrict__ Whh, const float* __restrict__ bhh,
    float* __restrict__ out)
{
    __shared__ short wi[192 * 64];
    __shared__ short wh[192 * 64];

    const int tid = threadIdx.x;
    for (int i = tid; i < 192 * 64; i += 512) {
        int n = i >> 6, k = i & 63;
        wi[LSW64(n, k)] = f2bf(Wih[n * 64 + k]);
        wh[LSW64(n, k)] = f2bf(Whh[n * 64 + k]);
    }
    __syncthreads();

    const int lane = tid & 63;
    const int w    = tid >> 6;
    const int nlo  = lane & 15;
    const int q    = lane >> 4;

    float bi[12], bh[12];
    #pragma unroll
    for (int t = 0; t < 12; ++t) { bi[t] = bih[16 * t + nlo]; bh[t] = bhh[16 * t + nlo]; }

    const int gw = blockIdx.x * 8 + w;
    const int nw = gridDim.x * 8;

    for (int tile = gw; tile < NN / 16; tile += nw) {
        const int n0 = tile * 16;
        f32x4 ai[12], ah[12];
        #pragma unroll
        for (int t = 0; t < 12; ++t) {
            ai[t][0] = bi[t]; ai[t][1] = bi[t]; ai[t][2] = bi[t]; ai[t][3] = bi[t];
            ah[t][0] = bh[t]; ah[t][1] = bh[t]; ah[t][2] = bh[t]; ah[t][3] = bh[t];
        }

        #pragma unroll
        for (int kk = 0; kk < 2; ++kk) {
            const int coff = (n0 + nlo) * ND + kk * 32 + q * 8;
            const float4 a0 = *(const float4*)(aggr + coff);
            const float4 a1 = *(const float4*)(aggr + coff + 4);
            const float4 x0 = *(const float4*)(x + coff);
            const float4 x1 = *(const float4*)(x + coff + 4);
            s16x8 fA, fX;
            fA[0] = f2bf(a0.x); fA[1] = f2bf(a0.y); fA[2] = f2bf(a0.z); fA[3] = f2bf(a0.w);
            fA[4] = f2bf(a1.x); fA[5] = f2bf(a1.y); fA[6] = f2bf(a1.z); fA[7] = f2bf(a1.w);
            fX[0] = f2bf(x0.x); fX[1] = f2bf(x0.y); fX[2] = f2bf(x0.z); fX[3] = f2bf(x0.w);
            fX[4] = f2bf(x1.x); fX[5] = f2bf(x1.y); fX[6] = f2bf(x1.z); fX[7] = f2bf(x1.w);
            const int chunk = kk * 4 + q;
            #pragma unroll
            for (int t = 0; t < 12; ++t) {
                const int rb = 16 * t + nlo;
                const int boff = (rb << 6) + (((chunk) ^ (rb & 7)) << 3);
                const s16x8 bI = *(const s16x8*)(wi + boff);
                const s16x8 bH = *(const s16x8*)(wh + boff);
                ai[t] = __builtin_amdgcn_mfma_f32_16x16x32_bf16(fA, bI, ai[t], 0, 0, 0);
                ah[t] = __builtin_amdgcn_mfma_f32_16x16x32_bf16(fX, bH, ah[t], 0, 0, 0);
            }
        }

        #pragma unroll
        for (int t = 0; t < 4; ++t) {
            #pragma unroll
            for (int r = 0; r < 4; ++r) {
                const int node = n0 + q * 4 + r;
                const int c    = nlo + 16 * t;
                const float rr = 1.f / (1.f + __expf(-(ai[t][r] + ah[t][r])));
                const float zz = 1.f / (1.f + __expf(-(ai[t + 4][r] + ah[t + 4][r])));
                const float nv = ai[t + 8][r] + rr * ah[t + 8][r];
                const float nn = 2.f / (1.f + __expf(-2.f * nv)) - 1.f;   // tanh
                const float xv = x[node * ND + c];
                out[node * ND + c] = (1.f - zz) * nn + zz * xv;
            }
        }
    }
}

extern "C" void kernel_launch(void* const* d_in, const int* in_sizes, int n_in,
                              void* d_out, int out_size, void* d_ws, size_t ws_size,
                              hipStream_t stream) {
    const float* x   = (const float*)d_in[0];
    const int*   ei  = (const int*)d_in[1];
    const float* ea  = (const float*)d_in[2];
    const float* W1  = (const float*)d_in[3];
    const float* b1  = (const float*)d_in[4];
    const float* W2  = (const float*)d_in[5];
    const float* b2  = (const float*)d_in[6];
    const float* Wih = (const float*)d_in[7];
    const float* bih = (const float*)d_in[8];
    const float* Whh = (const float*)d_in[9];
    const float* bhh = (const float*)d_in[10];
    float* out = (float*)d_out;

    // workspace layout (~57.7 MB)
    char* ws = (char*)d_ws;
    float* aggr    = (float*)(ws);                 // 25,600,000 B (msg output)
    // tmp edge buffers alias onto aggr (dead before msg writes it):
    int2*  tsd     = (int2*) (ws);                 // 12,800,000 B
    float* tea     = (float*)(ws + 12800000);      //  6,400,000 B
    short* xb      = (short*)(ws + 25600000);      // 12,800,000 B
    int2*  rsd     = (int2*) (ws + 38400000);      // 12,800,000 B (src,dst)
    float* rea     = (float*)(ws + 51200000);      //  6,400,000 B
    int*   gHistA  = (int*)  (ws + 57600000);      //     64,000 B (250*64 ints)
    int*   rowptrB = (int*)  (ws + 57664000);      //     25,004 B (6251 ints)
    int*   ticket  = (int*)  (ws + 57689004);      //          4 B

    hipLaunchKernelGGL(conv_bf16, dim3(512), dim3(256), 0, stream, x, xb);
    hipLaunchKernelGGL(histA, dim3(NBA), dim3(1024), 0, stream, ei, gHistA);
    hipLaunchKernelGGL(scanA, dim3(1), dim3(1024), 0, stream, gHistA, ticket);
    hipLaunchKernelGGL(scatterA, dim3(NBA), dim3(1024), 0, stream,
                       ei, ea, gHistA, tsd, tea);
    hipLaunchKernelGGL(scatterB, dim3(NCB), dim3(1024), 0, stream,
                       tsd, tea, gHistA, rsd, rea, rowptrB);
    hipLaunchKernelGGL(msg_mfma3, dim3(512), dim3(512), 0, stream,
                       xb, rsd, rea, rowptrB, ticket, W1, b1, W2, b2, aggr);
    hipLaunchKernelGGL(gru_mfma, dim3(256), dim3(512), 0, stream,
                       x, aggr, Wih, bih, Whh, bhh, out);
}